// Round 5
// baseline (915.723 us; speedup 1.0000x reference)
//
#include <hip/hip_runtime.h>
#include <stdint.h>

typedef int   v4i __attribute__((ext_vector_type(4)));
typedef float v4f __attribute__((ext_vector_type(4)));

// LDS map:
//   [0, 2*13824)  act slots: hi at l*2304 + b*144 + k, lo at +6912
//   BIAS_OFF      fp32 bias [l][type R,Z,NX,NH][h]  (6144 B)
//   FC_OFF        fc i8 A-frags, 2 blocks of 1KB
//   WLDS_OFF      Nh weight frags [wave][l*2+kh][lane]*16B  (48 KB)
#define SLOT_SZ  13824
#define LO_OFF   6912
#define BIAS_OFF (2*SLOT_SZ)            // 27648
#define FC_OFF   (BIAS_OFF + 6144)      // 33792
#define WLDS_OFF (FC_OFF + 2048)        // 35840
#define SMEM_SZ  (WLDS_OFF + 49152)     // 84992 (>64K: opt-in)

#define QW   1436.84056f      // 127/s, s = 1/sqrt(128)
#define C1f  4.38394754e-5f   // s*8/127^2  (hi-accum scale)
#define C2f  3.45193507e-7f   // C1/127     (lo-accum scale)

#define MFMA(A,B,C) __builtin_amdgcn_mfma_i32_16x16x64_i8(A, B, C, 0, 0, 0)

__device__ __forceinline__ float sigm(float x) {
  return __builtin_amdgcn_rcpf(1.f + __expf(-x));
}
__device__ __forceinline__ float tanh_(float x) {
  return 1.f - 2.f * __builtin_amdgcn_rcpf(1.f + __expf(2.f * x));
}

// i8 weight image (unchanged): blk = l*12 + o*2 + kh; o: 0 Rx,1 Rh,2 Zx,3 Zh,4 Nx,5 Nh.
// lane(g=lane&15, q=lane>>4) holds W[row g][k = kh*64 + q*16 + j], j=0..15.
__global__ void prep_weights(const float* __restrict__ Wih,
                             const float* __restrict__ Whh,
                             int8_t* __restrict__ img) {
  int bid = blockIdx.x, lane = threadIdx.x;          // 288 blocks x 64
  int w = bid / 36, blk = bid % 36;
  int l = blk / 12, rem = blk % 12, o = rem >> 1, kh = rem & 1;
  const float* M = (o & 1) ? Whh : Wih;
  int row = (o >> 1) * 128 + w * 16 + (lane & 15);
  int k0 = kh * 64 + (lane >> 4) * 16;
  const float* src = M + l * 49152 + row * 128 + k0;
  int words[4];
  #pragma unroll
  for (int j4 = 0; j4 < 4; ++j4) {
    unsigned wd = 0;
    #pragma unroll
    for (int j = 0; j < 4; ++j) {
      int q = (int)rintf(src[j4 * 4 + j] * QW);
      wd |= ((unsigned)(q & 255)) << (8 * j);
    }
    words[j4] = (int)wd;
  }
  *(v4i*)(img + (((long)bid) * 64 + lane) * 16) = *(const v4i*)words;
}

__global__ __launch_bounds__(512, 2)
void gru_main(const float* __restrict__ hiddens, const float* __restrict__ bih,
              const float* __restrict__ bhh, const float* __restrict__ fcw,
              const float* __restrict__ fcb, const int8_t* __restrict__ img,
              float* __restrict__ out) {
  extern __shared__ char smem[];
  const int tid = threadIdx.x, wg = blockIdx.x;
  const int lane = tid & 63, w = tid >> 6, col = lane & 15, q = lane >> 4;

  // ---- 30 weight frags in regs (kept: c%12 < 10 -> Rx,Rh,Zx,Zh,Nx pairs) ----
  v4i wr[30];
  #pragma unroll
  for (int i = 0; i < 30; ++i) {
    int blk = (i / 10) * 12 + (i % 10);
    wr[i] = *(const v4i*)(img + (((long)(w * 36 + blk)) * 64 + lane) * 16);
  }
  // ---- Nh weight frags (6 per wave) into LDS ----
  #pragma unroll
  for (int j = 0; j < 6; ++j) {
    int blk = (j >> 1) * 12 + 10 + (j & 1);
    *(v4i*)(smem + WLDS_OFF + w * 6144 + j * 1024 + lane * 16) =
        *(const v4i*)(img + (((long)(w * 36 + blk)) * 64 + lane) * 16);
  }
  // ---- fc i8 A-frags in LDS ----
  if (tid < 128) {
    int kh = tid >> 6, ln = tid & 63, c2 = ln & 15, q2 = ln >> 4;
    int words[4] = {0, 0, 0, 0};
    if (c2 < 2) {
      const float* src = fcw + c2 * 128 + kh * 64 + q2 * 16;
      #pragma unroll
      for (int j4 = 0; j4 < 4; ++j4) {
        unsigned wd = 0;
        #pragma unroll
        for (int j = 0; j < 4; ++j) {
          int qv = (int)rintf(src[j4 * 4 + j] * QW);
          wd |= ((unsigned)(qv & 255)) << (8 * j);
        }
        words[j4] = (int)wd;
      }
    }
    *(v4i*)(smem + FC_OFF + kh * 1024 + ln * 16) = *(const v4i*)words;
  }
  // ---- bias table in LDS: [l][type][h] fp32 ----
  for (int i = tid; i < 1536; i += 512) {
    int l = i >> 9, type = (i >> 7) & 3, h = i & 127;
    float bv;
    if      (type == 0) bv = bih[l * 384 + h]       + bhh[l * 384 + h];
    else if (type == 1) bv = bih[l * 384 + 128 + h] + bhh[l * 384 + 128 + h];
    else if (type == 2) bv = bih[l * 384 + 256 + h];
    else                bv = bhh[l * 384 + 256 + h];
    *(float*)(smem + BIAS_OFF + i * 4) = bv;
  }
  // ---- act slot0 init (hi/lo, 15.875 scale covers |h_init|<=8) ----
  for (int i = tid; i < 6144; i += 512) {
    int l = i >> 11, b = (i >> 7) & 15, h = i & 127;
    float v = hiddens[((long)(wg * 16 + b)) * 384 + l * 128 + h];
    float f = v * 15.875f, fhi = rintf(f);
    *(int8_t*)(smem + l * 2304 + b * 144 + h)          = (int8_t)(int)fhi;
    *(int8_t*)(smem + l * 2304 + b * 144 + h + LO_OFF) = (int8_t)(int)rintf((f - fhi) * 127.f);
  }
  // ---- h-state in regs: hst[l][r] = h[l][w*16+q*4+r][batch=col] ----
  v4f hst[3];
  #pragma unroll
  for (int l = 0; l < 3; ++l)
    #pragma unroll
    for (int r = 0; r < 4; ++r)
      hst[l][r] = hiddens[((long)(wg * 16 + col)) * 384 + l * 128 + w * 16 + q * 4 + r];

  const float fcb0 = fcb[0], fcb1 = fcb[1];
  __syncthreads();

  const char* fragb = smem + col * 144 + q * 16;   // B-frag lane base (n=col=batch)
  char* ewb = smem + col * 144 + w * 16 + q * 4;   // EW b32 write base
  const char* biasb = smem + BIAS_OFF + (w * 16 + q * 4) * 4;
  const char* wldsp = smem + WLDS_OFF + w * 6144 + lane * 16;

#define FC_BLOCK(FCT, XOFF) { \
  if (w == ((FCT) & 3)) { \
    v4i dh = {0,0,0,0}, dl = {0,0,0,0}; \
    _Pragma("unroll") \
    for (int kh = 0; kh < 2; ++kh) { \
      v4i fxh = *(const v4i*)(fragb + (XOFF) + kh * 64); \
      v4i fxl = *(const v4i*)(fragb + (XOFF) + kh * 64 + LO_OFF); \
      v4i fw  = *(const v4i*)(smem + FC_OFF + kh * 1024 + lane * 16); \
      dh = MFMA(fw, fxh, dh); dl = MFMA(fw, fxl, dl); } \
    if (q == 0) { float2 o2; \
      o2.x = fcb0 + C1f * (float)dh[0] + C2f * (float)dl[0]; \
      o2.y = fcb1 + C1f * (float)dh[1] + C2f * (float)dl[1]; \
      *(float2*)(out + (((long)(wg * 16 + col)) * 256 + ((FCT) - 1)) * 2) = o2; } } }

#define EW_STORE(L, WOFF, Rh, Rl, Zh, Zl, Xh, Xl, Hh, Hl) { \
  v4f bRv = *(const v4f*)(biasb + ((L) * 4 + 0) * 512); \
  v4f bZv = *(const v4f*)(biasb + ((L) * 4 + 1) * 512); \
  v4f bXv = *(const v4f*)(biasb + ((L) * 4 + 2) * 512); \
  v4f bHv = *(const v4f*)(biasb + ((L) * 4 + 3) * 512); \
  unsigned hiw = 0, low = 0; \
  _Pragma("unroll") \
  for (int r = 0; r < 4; ++r) { \
    float gR = bRv[r] + C1f * (float)Rh[r] + C2f * (float)Rl[r]; \
    float gZ = bZv[r] + C1f * (float)Zh[r] + C2f * (float)Zl[r]; \
    float gX = bXv[r] + C1f * (float)Xh[r] + C2f * (float)Xl[r]; \
    float gH = bHv[r] + C1f * (float)Hh[r] + C2f * (float)Hl[r]; \
    float rg = sigm(gR), zg = sigm(gZ); \
    float ng = tanh_(gX + rg * gH); \
    float hn = ng + zg * (hst[L][r] - ng); \
    hst[L][r] = hn; \
    float f = hn * 15.875f, fhi = rintf(f); \
    hiw |= ((unsigned)(((int)fhi) & 255)) << (8 * r); \
    low |= ((unsigned)(((int)rintf((f - fhi) * 127.f)) & 255)) << (8 * r); } \
  *(unsigned*)(ewb + (WOFF)) = hiw; \
  *(unsigned*)(ewb + (WOFF) + LO_OFF) = low; }

// One phase: x-side MFMAs of layer L into cur accums (+FC), hoist h-side of
// layer HL into next accums (independent of EW -> overlaps), EW(L), barrier.
#define PHASE(L, XV, XOFF, HV, HL, HOFF, cRh,cRl,cZh,cZl,cHh,cHl, \
              nRh,nRl,nZh,nZl,nHh,nHl, WOFF, FCV, FCT) { \
  v4i Xh = {0,0,0,0}, Xl = {0,0,0,0}; \
  if (XV) { \
    v4i xh0 = *(const v4i*)(fragb + (XOFF)); \
    v4i xh1 = *(const v4i*)(fragb + (XOFF) + 64); \
    v4i xl0 = *(const v4i*)(fragb + (XOFF) + LO_OFF); \
    v4i xl1 = *(const v4i*)(fragb + (XOFF) + LO_OFF + 64); \
    cRh = MFMA(wr[(L)*10+0], xh0, cRh); cRh = MFMA(wr[(L)*10+1], xh1, cRh); \
    cRl = MFMA(wr[(L)*10+0], xl0, cRl); cRl = MFMA(wr[(L)*10+1], xl1, cRl); \
    cZh = MFMA(wr[(L)*10+4], xh0, cZh); cZh = MFMA(wr[(L)*10+5], xh1, cZh); \
    cZl = MFMA(wr[(L)*10+4], xl0, cZl); cZl = MFMA(wr[(L)*10+5], xl1, cZl); \
    Xh  = MFMA(wr[(L)*10+8], xh0, Xh);  Xh  = MFMA(wr[(L)*10+9], xh1, Xh); \
    Xl  = MFMA(wr[(L)*10+8], xl0, Xl);  Xl  = MFMA(wr[(L)*10+9], xl1, Xl); \
    if (FCV) FC_BLOCK(FCT, XOFF) \
  } \
  nRh = (v4i){0,0,0,0}; nRl = (v4i){0,0,0,0}; nZh = (v4i){0,0,0,0}; \
  nZl = (v4i){0,0,0,0}; nHh = (v4i){0,0,0,0}; nHl = (v4i){0,0,0,0}; \
  if (HV) { \
    v4i hh0 = *(const v4i*)(fragb + (HOFF)); \
    v4i hh1 = *(const v4i*)(fragb + (HOFF) + 64); \
    v4i hl0 = *(const v4i*)(fragb + (HOFF) + LO_OFF); \
    v4i hl1 = *(const v4i*)(fragb + (HOFF) + LO_OFF + 64); \
    v4i wn0 = *(const v4i*)(wldsp + (HL) * 2048); \
    v4i wn1 = *(const v4i*)(wldsp + (HL) * 2048 + 1024); \
    nRh = MFMA(wr[(HL)*10+2], hh0, nRh); nRh = MFMA(wr[(HL)*10+3], hh1, nRh); \
    nRl = MFMA(wr[(HL)*10+2], hl0, nRl); nRl = MFMA(wr[(HL)*10+3], hl1, nRl); \
    nZh = MFMA(wr[(HL)*10+6], hh0, nZh); nZh = MFMA(wr[(HL)*10+7], hh1, nZh); \
    nZl = MFMA(wr[(HL)*10+6], hl0, nZl); nZl = MFMA(wr[(HL)*10+7], hl1, nZl); \
    nHh = MFMA(wn0, hh0, nHh); nHh = MFMA(wn1, hh1, nHh); \
    nHl = MFMA(wn0, hl0, nHl); nHl = MFMA(wn1, hl1, nHl); \
  } \
  EW_STORE(L, WOFF, cRh, cRl, cZh, cZl, Xh, Xl, cHh, cHl) \
  __syncthreads(); }

  v4i A_Rh, A_Rl, A_Zh, A_Zl, A_Hh, A_Hl;
  v4i B_Rh, B_Rl, B_Zh, B_Zl, B_Hh, B_Hl;

  // ---- prologue: pre-hoist h-side of layer 0 (init acts, slot0) into A ----
  {
    A_Rh = (v4i){0,0,0,0}; A_Rl = (v4i){0,0,0,0}; A_Zh = (v4i){0,0,0,0};
    A_Zl = (v4i){0,0,0,0}; A_Hh = (v4i){0,0,0,0}; A_Hl = (v4i){0,0,0,0};
    v4i hh0 = *(const v4i*)(fragb + 0);
    v4i hh1 = *(const v4i*)(fragb + 64);
    v4i hl0 = *(const v4i*)(fragb + LO_OFF);
    v4i hl1 = *(const v4i*)(fragb + LO_OFF + 64);
    v4i wn0 = *(const v4i*)(wldsp + 0);
    v4i wn1 = *(const v4i*)(wldsp + 1024);
    A_Rh = MFMA(wr[2], hh0, A_Rh); A_Rh = MFMA(wr[3], hh1, A_Rh);
    A_Rl = MFMA(wr[2], hl0, A_Rl); A_Rl = MFMA(wr[3], hl1, A_Rl);
    A_Zh = MFMA(wr[6], hh0, A_Zh); A_Zh = MFMA(wr[7], hh1, A_Zh);
    A_Zl = MFMA(wr[6], hl0, A_Zl); A_Zl = MFMA(wr[7], hl1, A_Zl);
    A_Hh = MFMA(wn0, hh0, A_Hh);   A_Hh = MFMA(wn1, hh1, A_Hh);
    A_Hl = MFMA(wn0, hl0, A_Hl);   A_Hl = MFMA(wn1, hl1, A_Hl);
  }
  // ---- t = 0 (reads init slot0, writes slot1): x0 = 0 ----
  PHASE(0, 0, 0, 1, 1, 1*2304,
        A_Rh,A_Rl,A_Zh,A_Zl,A_Hh,A_Hl, B_Rh,B_Rl,B_Zh,B_Zl,B_Hh,B_Hl,
        SLOT_SZ + 0, 0, 0)
  PHASE(1, 1, SLOT_SZ + 0, 1, 2, 2*2304,
        B_Rh,B_Rl,B_Zh,B_Zl,B_Hh,B_Hl, A_Rh,A_Rl,A_Zh,A_Zl,A_Hh,A_Hl,
        SLOT_SZ + 1*2304, 0, 0)
  PHASE(2, 1, SLOT_SZ + 1*2304, 1, 0, SLOT_SZ + 0,
        A_Rh,A_Rl,A_Zh,A_Zl,A_Hh,A_Hl, B_Rh,B_Rl,B_Zh,B_Zl,B_Hh,B_Hl,
        SLOT_SZ + 2*2304, 0, 0)

  // ---- main: steps T (odd, so=SLOT sn=0) and T+1 (even, so=0 sn=SLOT) ----
  #pragma unroll 1
  for (int ti = 0; ti < 127; ++ti) {
    const int T = 2 * ti + 1;
    PHASE(0, 1, SLOT_SZ + 2*2304, 1, 1, SLOT_SZ + 1*2304,
          B_Rh,B_Rl,B_Zh,B_Zl,B_Hh,B_Hl, A_Rh,A_Rl,A_Zh,A_Zl,A_Hh,A_Hl,
          0, 1, T)
    PHASE(1, 1, 0, 1, 2, SLOT_SZ + 2*2304,
          A_Rh,A_Rl,A_Zh,A_Zl,A_Hh,A_Hl, B_Rh,B_Rl,B_Zh,B_Zl,B_Hh,B_Hl,
          1*2304, 0, 0)
    PHASE(2, 1, 1*2304, 1, 0, 0,
          B_Rh,B_Rl,B_Zh,B_Zl,B_Hh,B_Hl, A_Rh,A_Rl,A_Zh,A_Zl,A_Hh,A_Hl,
          2*2304, 0, 0)
    PHASE(0, 1, 2*2304, 1, 1, 1*2304,
          A_Rh,A_Rl,A_Zh,A_Zl,A_Hh,A_Hl, B_Rh,B_Rl,B_Zh,B_Zl,B_Hh,B_Hl,
          SLOT_SZ + 0, 1, T + 1)
    PHASE(1, 1, SLOT_SZ + 0, 1, 2, 2*2304,
          B_Rh,B_Rl,B_Zh,B_Zl,B_Hh,B_Hl, A_Rh,A_Rl,A_Zh,A_Zl,A_Hh,A_Hl,
          SLOT_SZ + 1*2304, 0, 0)
    PHASE(2, 1, SLOT_SZ + 1*2304, 1, 0, SLOT_SZ + 0,
          A_Rh,A_Rl,A_Zh,A_Zl,A_Hh,A_Hl, B_Rh,B_Rl,B_Zh,B_Zl,B_Hh,B_Hl,
          SLOT_SZ + 2*2304, 0, 0)
  }

  // ---- epilogue: t = 255 (so=SLOT, sn=0) ----
  PHASE(0, 1, SLOT_SZ + 2*2304, 1, 1, SLOT_SZ + 1*2304,
        B_Rh,B_Rl,B_Zh,B_Zl,B_Hh,B_Hl, A_Rh,A_Rl,A_Zh,A_Zl,A_Hh,A_Hl,
        0, 1, 255)
  PHASE(1, 1, 0, 1, 2, SLOT_SZ + 2*2304,
        A_Rh,A_Rl,A_Zh,A_Zl,A_Hh,A_Hl, B_Rh,B_Rl,B_Zh,B_Zl,B_Hh,B_Hl,
        1*2304, 0, 0)
  PHASE(2, 1, 1*2304, 0, 0, 0,
        B_Rh,B_Rl,B_Zh,B_Zl,B_Hh,B_Hl, A_Rh,A_Rl,A_Zh,A_Zl,A_Hh,A_Hl,
        2*2304, 0, 0)

  // ---- final FC for t=255 (l2 acts in slot0) ----
  if (w == 0) {
    v4i dh = {0,0,0,0}, dl = {0,0,0,0};
    #pragma unroll
    for (int kh = 0; kh < 2; ++kh) {
      v4i fxh = *(const v4i*)(fragb + 2*2304 + kh * 64);
      v4i fxl = *(const v4i*)(fragb + 2*2304 + kh * 64 + LO_OFF);
      v4i fw  = *(const v4i*)(smem + FC_OFF + kh * 1024 + lane * 16);
      dh = MFMA(fw, fxh, dh); dl = MFMA(fw, fxl, dl);
    }
    if (q == 0) {
      float2 o2;
      o2.x = fcb0 + C1f * (float)dh[0] + C2f * (float)dl[0];
      o2.y = fcb1 + C1f * (float)dh[1] + C2f * (float)dl[1];
      *(float2*)(out + (((long)(wg * 16 + col)) * 256 + 255) * 2) = o2;
    }
  }
}

extern "C" void kernel_launch(void* const* d_in, const int* in_sizes, int n_in,
                              void* d_out, int out_size, void* d_ws, size_t ws_size,
                              hipStream_t stream) {
  (void)in_sizes; (void)n_in; (void)out_size; (void)ws_size;
  const float* hiddens = (const float*)d_in[0];
  const float* Wih     = (const float*)d_in[1];
  const float* Whh     = (const float*)d_in[2];
  const float* bih     = (const float*)d_in[3];
  const float* bhh     = (const float*)d_in[4];
  const float* fcw     = (const float*)d_in[5];
  const float* fcb     = (const float*)d_in[6];
  int8_t* img = (int8_t*)d_ws;   // 288 KB weight image
  float* out = (float*)d_out;

  hipFuncSetAttribute(reinterpret_cast<const void*>(gru_main),
                      hipFuncAttributeMaxDynamicSharedMemorySize, SMEM_SZ);

  prep_weights<<<288, 64, 0, stream>>>(Wih, Whh, img);
  gru_main<<<64, 512, SMEM_SZ, stream>>>(hiddens, bih, bhh, fcw, fcb, img, out);
}

// Round 6
// 839.149 us; speedup vs baseline: 1.0913x; 1.0913x over previous
//
#include <hip/hip_runtime.h>
#include <stdint.h>

typedef int   v4i __attribute__((ext_vector_type(4)));
typedef float v4f __attribute__((ext_vector_type(4)));

// LDS map:
//   [0, 2*13824)  act slots: hi at l*2304 + b*144 + k, lo at +6912
//   BIAS_OFF      fp32 PRE-SCALED bias [l][type R,Z,NX,NH][h]  (6144 B)
//   FC_OFF        fc i8 A-frags, 2 blocks of 1KB
#define SLOT_SZ  13824
#define LO_OFF   6912
#define BIAS_OFF (2*SLOT_SZ)            // 27648
#define FC_OFF   (BIAS_OFF + 6144)      // 33792
#define SMEM_SZ  (FC_OFF + 2048)        // 35840

#define QW   1436.84056f      // 127/s, s = 1/sqrt(128)
#define C1f  4.38394754e-5f   // s*8/127^2  (hi-accum scale)
#define C2f  3.45193507e-7f   // C1/127     (lo-accum scale)
#define L2E  1.44269504f
// folded gate-combine constants: sigmoid gates carry -log2e, tanh gates 2*log2e
#define CR1  (-(L2E)*C1f)
#define CR2  (-(L2E)*C2f)
#define CX1  (2.0f*L2E*C1f)
#define CX2  (2.0f*L2E*C2f)

#define MFMA(A,B,C) __builtin_amdgcn_mfma_i32_16x16x64_i8(A, B, C, 0, 0, 0)

// i8 weight image (unchanged): blk = l*12 + o*2 + kh; o: 0 Rx,1 Rh,2 Zx,3 Zh,4 Nx,5 Nh.
// lane(g=lane&15, q=lane>>4) holds W[row g][k = kh*64 + q*16 + j], j=0..15.
__global__ void prep_weights(const float* __restrict__ Wih,
                             const float* __restrict__ Whh,
                             int8_t* __restrict__ img) {
  int bid = blockIdx.x, lane = threadIdx.x;          // 288 blocks x 64
  int w = bid / 36, blk = bid % 36;
  int l = blk / 12, rem = blk % 12, o = rem >> 1, kh = rem & 1;
  const float* M = (o & 1) ? Whh : Wih;
  int row = (o >> 1) * 128 + w * 16 + (lane & 15);
  int k0 = kh * 64 + (lane >> 4) * 16;
  const float* src = M + l * 49152 + row * 128 + k0;
  int words[4];
  #pragma unroll
  for (int j4 = 0; j4 < 4; ++j4) {
    unsigned wd = 0;
    #pragma unroll
    for (int j = 0; j < 4; ++j) {
      int q = (int)rintf(src[j4 * 4 + j] * QW);
      wd |= ((unsigned)(q & 255)) << (8 * j);
    }
    words[j4] = (int)wd;
  }
  *(v4i*)(img + (((long)bid) * 64 + lane) * 16) = *(const v4i*)words;
}

__global__ __launch_bounds__(512, 2)
void gru_main(const float* __restrict__ hiddens, const float* __restrict__ bih,
              const float* __restrict__ bhh, const float* __restrict__ fcw,
              const float* __restrict__ fcb, const int8_t* __restrict__ img,
              float* __restrict__ out) {
  extern __shared__ char smem[];
  const int tid = threadIdx.x, wg = blockIdx.x;
  const int lane = tid & 63, w = tid >> 6, col = lane & 15, q = lane >> 4;

  // ---- ALL 36 weight frags in registers (144 regs) ----
  v4i wr[36];
  #pragma unroll
  for (int i = 0; i < 36; ++i)
    wr[i] = *(const v4i*)(img + (((long)(w * 36 + i)) * 64 + lane) * 16);

  // ---- fc i8 A-frags in LDS ----
  if (tid < 128) {
    int kh = tid >> 6, ln = tid & 63, c2 = ln & 15, q2 = ln >> 4;
    int words[4] = {0, 0, 0, 0};
    if (c2 < 2) {
      const float* src = fcw + c2 * 128 + kh * 64 + q2 * 16;
      #pragma unroll
      for (int j4 = 0; j4 < 4; ++j4) {
        unsigned wd = 0;
        #pragma unroll
        for (int j = 0; j < 4; ++j) {
          int qv = (int)rintf(src[j4 * 4 + j] * QW);
          wd |= ((unsigned)(qv & 255)) << (8 * j);
        }
        words[j4] = (int)wd;
      }
    }
    *(v4i*)(smem + FC_OFF + kh * 1024 + ln * 16) = *(const v4i*)words;
  }
  // ---- bias table in LDS, PRE-SCALED for exp2-form gates ----
  for (int i = tid; i < 1536; i += 512) {
    int l = i >> 9, type = (i >> 7) & 3, h = i & 127;
    float bv;
    if      (type == 0) bv = -L2E * (bih[l * 384 + h]       + bhh[l * 384 + h]);
    else if (type == 1) bv = -L2E * (bih[l * 384 + 128 + h] + bhh[l * 384 + 128 + h]);
    else if (type == 2) bv = 2.0f * L2E * bih[l * 384 + 256 + h];
    else                bv = 2.0f * L2E * bhh[l * 384 + 256 + h];
    *(float*)(smem + BIAS_OFF + i * 4) = bv;
  }
  // ---- act slot0 init (hi/lo) ----
  for (int i = tid; i < 6144; i += 512) {
    int l = i >> 11, b = (i >> 7) & 15, h = i & 127;
    float v = hiddens[((long)(wg * 16 + b)) * 384 + l * 128 + h];
    float f = v * 15.875f, fhi = rintf(f);
    *(int8_t*)(smem + l * 2304 + b * 144 + h)          = (int8_t)(int)fhi;
    *(int8_t*)(smem + l * 2304 + b * 144 + h + LO_OFF) = (int8_t)(int)rintf((f - fhi) * 127.f);
  }
  // ---- h-state in regs: hst[l][r] = h[l][w*16+q*4+r][batch=col] ----
  v4f hst[3];
  #pragma unroll
  for (int l = 0; l < 3; ++l)
    #pragma unroll
    for (int r = 0; r < 4; ++r)
      hst[l][r] = hiddens[((long)(wg * 16 + col)) * 384 + l * 128 + w * 16 + q * 4 + r];

  const float fcb0 = fcb[0], fcb1 = fcb[1];
  __syncthreads();

  const char* fragb = smem + col * 144 + q * 16;   // B-frag lane base (n=col=batch)
  char* ewb = smem + col * 144 + w * 16 + q * 4;   // EW b32 write base
  const char* biasb = smem + BIAS_OFF + (w * 16 + q * 4) * 4;

  v4i c2h[2], c2l[2];   // cached layer-2 read-slot frags (l0-x == l2-h data)

  #pragma unroll 1
  for (int t = 0; t < 256; ++t) {
    const int so = (t & 1) * SLOT_SZ;
    const int sn = SLOT_SZ - so;
    #pragma unroll
    for (int l = 0; l < 3; ++l) {
      // bias prefetch (independent of everything in this phase)
      v4f bRv = *(const v4f*)(biasb + (l * 4 + 0) * 512);
      v4f bZv = *(const v4f*)(biasb + (l * 4 + 1) * 512);
      v4f bXv = *(const v4f*)(biasb + (l * 4 + 2) * 512);
      v4f bHv = *(const v4f*)(biasb + (l * 4 + 3) * 512);
      v4i aRh = {0,0,0,0}, aRl = {0,0,0,0}, aZh = {0,0,0,0}, aZl = {0,0,0,0};
      v4i aXh = {0,0,0,0}, aXl = {0,0,0,0}, aHh = {0,0,0,0}, aHl = {0,0,0,0};
      // ---- x side (on the serial chain: issue first) ----
      if (l > 0 || t > 0) {
        #pragma unroll
        for (int kh = 0; kh < 2; ++kh) {
          v4i xh, xl;
          if (l == 0) {           // x = prev-step layer2 acts (read slot); cache
            xh = *(const v4i*)(fragb + so + 2 * 2304 + kh * 64);
            xl = *(const v4i*)(fragb + so + 2 * 2304 + kh * 64 + LO_OFF);
            c2h[kh] = xh; c2l[kh] = xl;
          } else {                // x = fresh layer l-1 acts (write slot)
            xh = *(const v4i*)(fragb + sn + (l - 1) * 2304 + kh * 64);
            xl = *(const v4i*)(fragb + sn + (l - 1) * 2304 + kh * 64 + LO_OFF);
          }
          aRh = MFMA(wr[l*12 + 0 + kh], xh, aRh);
          aRl = MFMA(wr[l*12 + 0 + kh], xl, aRl);
          aZh = MFMA(wr[l*12 + 4 + kh], xh, aZh);
          aZl = MFMA(wr[l*12 + 4 + kh], xl, aZl);
          aXh = MFMA(wr[l*12 + 8 + kh], xh, aXh);
          aXl = MFMA(wr[l*12 + 8 + kh], xl, aXl);
        }
      }
      // ---- h side ----
      #pragma unroll
      for (int kh = 0; kh < 2; ++kh) {
        v4i hh, hl;
        if (l == 2) {             // same bytes l0-x read this step
          if (t == 0) { c2h[kh] = *(const v4i*)(fragb + so + 2 * 2304 + kh * 64);
                        c2l[kh] = *(const v4i*)(fragb + so + 2 * 2304 + kh * 64 + LO_OFF); }
          hh = c2h[kh]; hl = c2l[kh];
        } else {
          hh = *(const v4i*)(fragb + so + l * 2304 + kh * 64);
          hl = *(const v4i*)(fragb + so + l * 2304 + kh * 64 + LO_OFF);
        }
        aRh = MFMA(wr[l*12 + 2 + kh], hh, aRh);
        aRl = MFMA(wr[l*12 + 2 + kh], hl, aRl);
        aZh = MFMA(wr[l*12 + 6 + kh], hh, aZh);
        aZl = MFMA(wr[l*12 + 6 + kh], hl, aZl);
        aHh = MFMA(wr[l*12 + 10 + kh], hh, aHh);
        aHl = MFMA(wr[l*12 + 10 + kh], hl, aHl);
      }
      // ---- lean EW: exp2-form gates, folded constants, fp32 state ----
      unsigned hiw = 0, low = 0;
      #pragma unroll
      for (int r = 0; r < 4; ++r) {
        float gR = fmaf(CR1, (float)aRh[r], fmaf(CR2, (float)aRl[r], bRv[r]));
        float gZ = fmaf(CR1, (float)aZh[r], fmaf(CR2, (float)aZl[r], bZv[r]));
        float gX = fmaf(CX1, (float)aXh[r], fmaf(CX2, (float)aXl[r], bXv[r]));
        float gH = fmaf(CX1, (float)aHh[r], fmaf(CX2, (float)aHl[r], bHv[r]));
        float rg = __builtin_amdgcn_rcpf(1.f + __builtin_amdgcn_exp2f(gR));
        float zg = __builtin_amdgcn_rcpf(1.f + __builtin_amdgcn_exp2f(gZ));
        float u  = __builtin_amdgcn_rcpf(1.f + __builtin_amdgcn_exp2f(fmaf(rg, gH, gX)));
        float ng = fmaf(-2.f, u, 1.f);
        float hn = fmaf(zg, hst[l][r] - ng, ng);
        hst[l][r] = hn;
        float f = hn * 15.875f, fhi = rintf(f);
        hiw |= ((unsigned)(((int)fhi) & 255)) << (8 * r);
        low |= ((unsigned)(((int)rintf((f - fhi) * 127.f)) & 255)) << (8 * r);
      }
      *(unsigned*)(ewb + sn + l * 2304)          = hiw;
      *(unsigned*)(ewb + sn + l * 2304 + LO_OFF) = low;
      __syncthreads();
    }
    // ---- FC epilogue (wave 0): reads layer-2 acts just written (write slot) ----
    if (w == 0) {
      v4i dh = {0,0,0,0}, dl = {0,0,0,0};
      #pragma unroll
      for (int kh = 0; kh < 2; ++kh) {
        v4i xh = *(const v4i*)(fragb + sn + 2 * 2304 + kh * 64);
        v4i xl = *(const v4i*)(fragb + sn + 2 * 2304 + kh * 64 + LO_OFF);
        v4i fw = *(const v4i*)(smem + FC_OFF + kh * 1024 + lane * 16);
        dh = MFMA(fw, xh, dh);
        dl = MFMA(fw, xl, dl);
      }
      if (q == 0) {
        float2 o2;
        o2.x = fcb0 + C1f * (float)dh[0] + C2f * (float)dl[0];
        o2.y = fcb1 + C1f * (float)dh[1] + C2f * (float)dl[1];
        *(float2*)(out + (((long)(wg * 16 + col)) * 256 + t) * 2) = o2;
      }
    }
  }
}

extern "C" void kernel_launch(void* const* d_in, const int* in_sizes, int n_in,
                              void* d_out, int out_size, void* d_ws, size_t ws_size,
                              hipStream_t stream) {
  (void)in_sizes; (void)n_in; (void)out_size; (void)ws_size;
  const float* hiddens = (const float*)d_in[0];
  const float* Wih     = (const float*)d_in[1];
  const float* Whh     = (const float*)d_in[2];
  const float* bih     = (const float*)d_in[3];
  const float* bhh     = (const float*)d_in[4];
  const float* fcw     = (const float*)d_in[5];
  const float* fcb     = (const float*)d_in[6];
  int8_t* img = (int8_t*)d_ws;   // 288 KB weight image
  float* out = (float*)d_out;

  prep_weights<<<288, 64, 0, stream>>>(Wih, Whh, img);
  gru_main<<<64, 512, SMEM_SZ, stream>>>(hiddens, bih, bhh, fcw, fcb, img, out);
}